// Round 6
// baseline (272.983 us; speedup 1.0000x reference)
//
#include <hip/hip_runtime.h>
#include <stdint.h>

#define NB 4096
#define QLEN 1024
#define NL 64
#define KLEN 32
#define NS (QLEN - KLEN + 1)   // 993

typedef __attribute__((ext_vector_type(8))) _Float16 half8;
typedef __attribute__((ext_vector_type(4))) float f32x4;

union fragh { uint32_t u[4]; half8 v; };

static __device__ __forceinline__ uint32_t pkh(float a, float b) {
    return __builtin_bit_cast(uint32_t, __builtin_amdgcn_cvt_pkrtz(a, b)); // v_cvt_pkrtz_f16_f32
}
static __device__ __forceinline__ float lo16f(uint32_t w) {
    return (float)__builtin_bit_cast(_Float16, (unsigned short)(w & 0xFFFFu));
}
static __device__ __forceinline__ float hi16f(uint32_t w) {
    return (float)__builtin_bit_cast(_Float16, (unsigned short)(w >> 16));
}

__global__ __launch_bounds__(256, 6) void shapelet_mfma_pipe(
    const float* __restrict__ ts,        // [B, Q]
    const float* __restrict__ shapelets, // [L, K]
    const float* __restrict__ fc_w,      // [2, L]
    const float* __restrict__ fc_b,      // [2]
    float* __restrict__ out)             // [B, 2]
{
    __shared__ __align__(16) uint32_t lds_pkE[544];   // f16(x[2i]) | f16(x[2i+1])<<16
    __shared__ __align__(16) uint32_t lds_pkO[544];   // f16(x[2i+1]) | f16(x[2i+2])<<16
    __shared__ __align__(16) float    lds_nwin[QLEN]; // -0.5*win_sq; -1e30 for s>=NS
    __shared__ __align__(16) float    lds_s4[264];    // per-thread 4-square partials
    __shared__ float lds_ssq[NL];
    __shared__ float lds_pm[4][NL];

    const int tid  = threadIdx.x;
    const int b    = blockIdx.x;
    const int lane = tid & 63;
    const int wave = tid >> 6;
    const int col  = lane & 15;
    const int kg   = lane >> 4;

    // --- pass 1: own float4 + next dword from global; pack f16; s4 partial ---
    float x0, x1, x2;
    {
        float4 v = reinterpret_cast<const float4*>(ts + (size_t)b * QLEN)[tid];
        x0 = v.x; x1 = v.y; x2 = v.z;
        float x3 = v.w;
        float x4g = (tid < 255) ? ts[(size_t)b * QLEN + 4 * tid + 4] : 0.0f;
        uint2 pe = { pkh(x0, x1), pkh(x2, x3) };
        uint2 po = { pkh(x1, x2), pkh(x3, x4g) };
        reinterpret_cast<uint2*>(lds_pkE)[tid] = pe;
        reinterpret_cast<uint2*>(lds_pkO)[tid] = po;
        lds_s4[tid] = fmaf(x0, x0, fmaf(x1, x1, fmaf(x2, x2, x3 * x3)));
    }
    if (tid < 32) { lds_pkE[512 + tid] = 0u; lds_pkO[512 + tid] = 0u; }
    if (tid < 8)  lds_s4[256 + tid] = 0.0f;

    // --- B fragments: fp16 RTZ, all 4 l-tiles (16 VGPR) ---
    fragh Bh[4];
    #pragma unroll
    for (int lt = 0; lt < 4; ++lt) {
        const float* sp = shapelets + (lt * 16 + col) * KLEN + kg * 8;
        float4 f0 = *reinterpret_cast<const float4*>(sp);
        float4 f1 = *reinterpret_cast<const float4*>(sp + 4);
        Bh[lt].u[0] = pkh(f0.x, f0.y);
        Bh[lt].u[1] = pkh(f0.z, f0.w);
        Bh[lt].u[2] = pkh(f1.x, f1.y);
        Bh[lt].u[3] = pkh(f1.z, f1.w);
    }

    // --- per-shapelet sum of squares (fp32, global reads, L2-cached) ---
    if (tid < NL) {
        const float* sp = shapelets + tid * KLEN;
        float s = 0.0f;
        #pragma unroll
        for (int k = 0; k < KLEN; ++k) s = fmaf(sp[k], sp[k], s);
        lds_ssq[tid] = s;
    }
    __syncthreads();

    // --- pass 2: win_sq from s4 partials + f16 sliding corrections ---
    {
        float s[8];
        #pragma unroll
        for (int j = 0; j < 8; ++j) s[j] = lds_s4[tid + j];
        float w0 = ((s[0] + s[1]) + (s[2] + s[3])) + ((s[4] + s[5]) + (s[6] + s[7]));
        uint32_t cw0 = lds_pkE[2 * (tid + 8)];
        uint32_t cw1 = lds_pkE[2 * (tid + 8) + 1];
        float x32 = lo16f(cw0), x33 = hi16f(cw0), x34 = lo16f(cw1);
        float w1 = fmaf(x32, x32, fmaf(-x0, x0, w0));
        float w2 = fmaf(x33, x33, fmaf(-x1, x1, w1));
        float w3 = fmaf(x34, x34, fmaf(-x2, x2, w2));
        const int p0 = 4 * tid;
        float4 wv;
        wv.x = (p0 + 0 < NS) ? -0.5f * w0 : -1.0e30f;
        wv.y = (p0 + 1 < NS) ? -0.5f * w1 : -1.0e30f;
        wv.z = (p0 + 2 < NS) ? -0.5f * w2 : -1.0e30f;
        wv.w = (p0 + 3 < NS) ? -0.5f * w3 : -1.0e30f;
        reinterpret_cast<float4*>(lds_nwin)[tid] = wv;
    }
    __syncthreads();

    // --- main loop: software-pipelined, 8 iters, 2 s-tiles each ---
    float rmax[4][4];
    #pragma unroll
    for (int lt = 0; lt < 4; ++lt)
        #pragma unroll
        for (int e = 0; e < 4; ++e) rmax[lt][e] = -3.0e38f;

    const int par = col & 1;
    const uint32_t* apk = par ? lds_pkO : lds_pkE;
    const int abase = ((col - par) >> 1) + kg * 4;

    fragh Aa, Ab;
    f32x4 ia, ib;
    {
        const uint32_t* ap = apk + 16 * wave + abase;   // s0 = 32*wave
        #pragma unroll
        for (int j = 0; j < 4; ++j) Aa.u[j] = ap[j];
        #pragma unroll
        for (int j = 0; j < 4; ++j) Ab.u[j] = ap[8 + j];
        ia = *reinterpret_cast<const f32x4*>(lds_nwin + 32 * wave + kg * 4);
        ib = *reinterpret_cast<const f32x4*>(lds_nwin + 32 * wave + 16 + kg * 4);
    }

    #pragma unroll 2
    for (int i = 0; i < 8; ++i) {
        fragh Pa, Pb;
        f32x4 pa, pb;
        if (i < 7) {   // prefetch next iteration before this one's MFMAs
            const int s0n = 32 * wave + 128 * (i + 1);
            const uint32_t* ap = apk + (s0n >> 1) + abase;
            #pragma unroll
            for (int j = 0; j < 4; ++j) Pa.u[j] = ap[j];
            #pragma unroll
            for (int j = 0; j < 4; ++j) Pb.u[j] = ap[8 + j];
            pa = *reinterpret_cast<const f32x4*>(lds_nwin + s0n + kg * 4);
            pb = *reinterpret_cast<const f32x4*>(lds_nwin + s0n + 16 + kg * 4);
        }

        #pragma unroll
        for (int lt = 0; lt < 4; ++lt) {
            f32x4 aa = __builtin_amdgcn_mfma_f32_16x16x32_f16(Aa.v, Bh[lt].v, ia, 0, 0, 0);
            f32x4 ab = __builtin_amdgcn_mfma_f32_16x16x32_f16(Ab.v, Bh[lt].v, ib, 0, 0, 0);
            #pragma unroll
            for (int e = 0; e < 4; ++e)
                rmax[lt][e] = fmaxf(fmaxf(aa[e], ab[e]), rmax[lt][e]);  // v_max3_f32
        }

        if (i < 7) { Aa = Pa; Ab = Pb; ia = pa; ib = pb; }
    }

    // --- reduce: within-lane, cross-kg (same col), cross-wave ---
    #pragma unroll
    for (int lt = 0; lt < 4; ++lt) {
        float v = fmaxf(fmaxf(rmax[lt][0], rmax[lt][1]),
                        fmaxf(rmax[lt][2], rmax[lt][3]));
        v = fmaxf(v, __shfl_xor(v, 16, 64));
        v = fmaxf(v, __shfl_xor(v, 32, 64));
        if (kg == 0) lds_pm[wave][lt * 16 + col] = v;
    }
    __syncthreads();

    if (wave == 0) {
        float m = fmaxf(fmaxf(lds_pm[0][lane], lds_pm[1][lane]),
                        fmaxf(lds_pm[2][lane], lds_pm[3][lane]));
        float f = (lds_ssq[lane] - 2.0f * m) * (1.0f / (float)KLEN);  // min dist

        float p0v = f * fc_w[lane];
        float p1v = f * fc_w[NL + lane];
        #pragma unroll
        for (int off = 32; off >= 1; off >>= 1) {
            p0v += __shfl_xor(p0v, off, 64);
            p1v += __shfl_xor(p1v, off, 64);
        }
        if (lane == 0) {
            out[(size_t)b * 2 + 0] = p0v + fc_b[0];
            out[(size_t)b * 2 + 1] = p1v + fc_b[1];
        }
    }
}

extern "C" void kernel_launch(void* const* d_in, const int* in_sizes, int n_in,
                              void* d_out, int out_size, void* d_ws, size_t ws_size,
                              hipStream_t stream) {
    const float* ts        = (const float*)d_in[0];
    const float* shapelets = (const float*)d_in[1];
    const float* fc_w      = (const float*)d_in[2];
    const float* fc_b      = (const float*)d_in[3];
    float* out = (float*)d_out;

    shapelet_mfma_pipe<<<NB, 256, 0, stream>>>(ts, shapelets, fc_w, fc_b, out);
}

// Round 7
// 28.569 us; speedup vs baseline: 9.5553x; 9.5553x over previous
//
#include <hip/hip_runtime.h>
#include <stdint.h>

#define NB 4096
#define QLEN 1024
#define NL 64
#define KLEN 32
#define NS (QLEN - KLEN + 1)   // 993

typedef __attribute__((ext_vector_type(8))) _Float16 half8;
typedef __attribute__((ext_vector_type(4))) float f32x4;

union fragh { uint32_t u[4]; half8 v; };

static __device__ __forceinline__ uint32_t pkh(float a, float b) {
    return __builtin_bit_cast(uint32_t, __builtin_amdgcn_cvt_pkrtz(a, b)); // v_cvt_pkrtz_f16_f32
}
static __device__ __forceinline__ float lo16f(uint32_t w) {
    return (float)__builtin_bit_cast(_Float16, (unsigned short)(w & 0xFFFFu));
}
static __device__ __forceinline__ float hi16f(uint32_t w) {
    return (float)__builtin_bit_cast(_Float16, (unsigned short)(w >> 16));
}

__global__ __launch_bounds__(256, 6) void shapelet_mfma_r7(
    const float* __restrict__ ts,        // [B, Q]
    const float* __restrict__ shapelets, // [L, K]
    const float* __restrict__ fc_w,      // [2, L]
    const float* __restrict__ fc_b,      // [2]
    float* __restrict__ out)             // [B, 2]
{
    __shared__ __align__(16) uint32_t lds_pkE[544];   // f16(x[2i]) | f16(x[2i+1])<<16
    __shared__ __align__(16) uint32_t lds_pkO[544];   // f16(x[2i+1]) | f16(x[2i+2])<<16
    __shared__ __align__(16) float    lds_nwin[QLEN]; // -0.5*win_sq; -1e30 for s>=NS
    __shared__ __align__(16) float    lds_s4[264];    // per-thread 4-square partials
    __shared__ float lds_ssq[NL];
    __shared__ float lds_pm[4][NL];

    const int tid  = threadIdx.x;
    const int b    = blockIdx.x;
    const int lane = tid & 63;
    const int wave = tid >> 6;
    const int col  = lane & 15;
    const int kg   = lane >> 4;

    // --- pass 1: own float4 + next dword from global; pack f16; s4 partial ---
    float x0, x1, x2;
    {
        float4 v = reinterpret_cast<const float4*>(ts + (size_t)b * QLEN)[tid];
        x0 = v.x; x1 = v.y; x2 = v.z;
        float x3 = v.w;
        float x4g = (tid < 255) ? ts[(size_t)b * QLEN + 4 * tid + 4] : 0.0f;
        uint2 pe = { pkh(x0, x1), pkh(x2, x3) };
        uint2 po = { pkh(x1, x2), pkh(x3, x4g) };
        reinterpret_cast<uint2*>(lds_pkE)[tid] = pe;
        reinterpret_cast<uint2*>(lds_pkO)[tid] = po;
        lds_s4[tid] = fmaf(x0, x0, fmaf(x1, x1, fmaf(x2, x2, x3 * x3)));
    }
    if (tid < 32) { lds_pkE[512 + tid] = 0u; lds_pkO[512 + tid] = 0u; }
    if (tid < 8)  lds_s4[256 + tid] = 0.0f;

    // --- B fragments: fp16 RTZ, all 4 l-tiles (16 VGPR) ---
    fragh Bh[4];
    #pragma unroll
    for (int lt = 0; lt < 4; ++lt) {
        const float* sp = shapelets + (lt * 16 + col) * KLEN + kg * 8;
        float4 f0 = *reinterpret_cast<const float4*>(sp);
        float4 f1 = *reinterpret_cast<const float4*>(sp + 4);
        Bh[lt].u[0] = pkh(f0.x, f0.y);
        Bh[lt].u[1] = pkh(f0.z, f0.w);
        Bh[lt].u[2] = pkh(f1.x, f1.y);
        Bh[lt].u[3] = pkh(f1.z, f1.w);
    }

    // --- per-shapelet sum of squares (fp32, global reads, L2-cached) ---
    if (tid < NL) {
        const float* sp = shapelets + tid * KLEN;
        float s = 0.0f;
        #pragma unroll
        for (int k = 0; k < KLEN; ++k) s = fmaf(sp[k], sp[k], s);
        lds_ssq[tid] = s;
    }
    __syncthreads();

    // --- pass 2: win_sq from s4 partials + f16 sliding corrections ---
    {
        float s[8];
        #pragma unroll
        for (int j = 0; j < 8; ++j) s[j] = lds_s4[tid + j];
        float w0 = ((s[0] + s[1]) + (s[2] + s[3])) + ((s[4] + s[5]) + (s[6] + s[7]));
        uint32_t cw0 = lds_pkE[2 * (tid + 8)];
        uint32_t cw1 = lds_pkE[2 * (tid + 8) + 1];
        float x32 = lo16f(cw0), x33 = hi16f(cw0), x34 = lo16f(cw1);
        float w1 = fmaf(x32, x32, fmaf(-x0, x0, w0));
        float w2 = fmaf(x33, x33, fmaf(-x1, x1, w1));
        float w3 = fmaf(x34, x34, fmaf(-x2, x2, w2));
        const int p0 = 4 * tid;
        float4 wv;
        wv.x = (p0 + 0 < NS) ? -0.5f * w0 : -1.0e30f;
        wv.y = (p0 + 1 < NS) ? -0.5f * w1 : -1.0e30f;
        wv.z = (p0 + 2 < NS) ? -0.5f * w2 : -1.0e30f;
        wv.w = (p0 + 3 < NS) ? -0.5f * w3 : -1.0e30f;
        reinterpret_cast<float4*>(lds_nwin)[tid] = wv;
    }
    __syncthreads();

    // --- main loop: 8 iters, 2 s-tiles each, 1 fp16 MFMA per (tile, lt) ---
    // (round-5 known-good form: straight-line loads, no register rotation)
    float rmax[4][4];
    #pragma unroll
    for (int lt = 0; lt < 4; ++lt)
        #pragma unroll
        for (int e = 0; e < 4; ++e) rmax[lt][e] = -3.0e38f;

    const int par = col & 1;
    const uint32_t* apk = par ? lds_pkO : lds_pkE;
    const int abase = ((col - par) >> 1) + kg * 4;

    #pragma unroll 2
    for (int i = 0; i < 8; ++i) {
        const int s0 = 32 * wave + 128 * i;
        const uint32_t* ap = apk + (s0 >> 1) + abase;
        fragh Aa, Ab;
        #pragma unroll
        for (int j = 0; j < 4; ++j) Aa.u[j] = ap[j];
        #pragma unroll
        for (int j = 0; j < 4; ++j) Ab.u[j] = ap[8 + j];
        const f32x4 ia = *reinterpret_cast<const f32x4*>(lds_nwin + s0 + kg * 4);
        const f32x4 ib = *reinterpret_cast<const f32x4*>(lds_nwin + s0 + 16 + kg * 4);

        #pragma unroll
        for (int lt = 0; lt < 4; ++lt) {
            f32x4 aa = __builtin_amdgcn_mfma_f32_16x16x32_f16(Aa.v, Bh[lt].v, ia, 0, 0, 0);
            f32x4 ab = __builtin_amdgcn_mfma_f32_16x16x32_f16(Ab.v, Bh[lt].v, ib, 0, 0, 0);
            #pragma unroll
            for (int e = 0; e < 4; ++e)
                rmax[lt][e] = fmaxf(fmaxf(aa[e], ab[e]), rmax[lt][e]);  // v_max3_f32
        }
    }

    // --- reduce: within-lane, cross-kg (same col), cross-wave ---
    #pragma unroll
    for (int lt = 0; lt < 4; ++lt) {
        float v = fmaxf(fmaxf(rmax[lt][0], rmax[lt][1]),
                        fmaxf(rmax[lt][2], rmax[lt][3]));
        v = fmaxf(v, __shfl_xor(v, 16, 64));
        v = fmaxf(v, __shfl_xor(v, 32, 64));
        if (kg == 0) lds_pm[wave][lt * 16 + col] = v;
    }
    __syncthreads();

    if (wave == 0) {
        float m = fmaxf(fmaxf(lds_pm[0][lane], lds_pm[1][lane]),
                        fmaxf(lds_pm[2][lane], lds_pm[3][lane]));
        float f = (lds_ssq[lane] - 2.0f * m) * (1.0f / (float)KLEN);  // min dist

        float p0v = f * fc_w[lane];
        float p1v = f * fc_w[NL + lane];
        #pragma unroll
        for (int off = 32; off >= 1; off >>= 1) {
            p0v += __shfl_xor(p0v, off, 64);
            p1v += __shfl_xor(p1v, off, 64);
        }
        if (lane == 0) {
            out[(size_t)b * 2 + 0] = p0v + fc_b[0];
            out[(size_t)b * 2 + 1] = p1v + fc_b[1];
        }
    }
}

extern "C" void kernel_launch(void* const* d_in, const int* in_sizes, int n_in,
                              void* d_out, int out_size, void* d_ws, size_t ws_size,
                              hipStream_t stream) {
    const float* ts        = (const float*)d_in[0];
    const float* shapelets = (const float*)d_in[1];
    const float* fc_w      = (const float*)d_in[2];
    const float* fc_b      = (const float*)d_in[3];
    float* out = (float*)d_out;

    shapelet_mfma_r7<<<NB, 256, 0, stream>>>(ts, shapelets, fc_w, fc_b, out);
}